// Round 1
// 150.931 us; speedup vs baseline: 1.0503x; 1.0503x over previous
//
#include <hip/hip_runtime.h>

// SelfAttention B=2 S=2048 H=16 E=64, fp32 in/out, bf16 MFMA internally.
// Round 6: 32x32x16 MFMA + fully in-register P. The attn loop was
// LDS-bandwidth-bound (per blk-ktile: 8 waves x 20KB frags+P = 176KB).
// Changes: (a) 16x16x32 -> 32x32x16 MFMA halves A-operand bytes/FLOP;
// (b) 8 waves = 4 q-blocks(32q) x 2 key-blocks(32k) split the tile, no
// duplicated work; (c) P never touches LDS: cvt_pk_bf16 pairs +
// v_permlane32_swap_b32 redistribute QK^T output (D[col=q][row=key]) into
// PV B-fragments in registers (T12); (d) softmax denominator l = per-lane
// f32 sum (VALU), reduced over (kblk,hi) in epilogue via LDS; (e) CSHIFT
// folded into mask bias (mask ? -16 : -1e30), exp2 applied directly.
// Per blk-ktile LDS traffic: 8x8KB frags + 16KB staging = 80KB (2.2x less).
// Retained: fixed-shift log2-domain softmax (LOG2E folded into Q at proj),
// global_load_lds staging, double-buffered K/V, one barrier per k-tile,
// XOR-swizzled gmem layout (chunk c of row r at physical c^(r&7)), proj
// kernel unchanged.

#define BATCH 2
#define SEQ   2048
#define NH    16
#define DE    64
#define LDP   72     // proj internal tile stride
#define LDOF  68     // O f32 epilogue stride
#define NKT   (SEQ / 64)
#define LOG2E 1.44269504088896340736f
#define CSHIFT 16.0f

using bf16x8   = __attribute__((ext_vector_type(8))) __bf16;
using bf16x4   = __attribute__((ext_vector_type(4))) __bf16;
using bf16x2   = __attribute__((ext_vector_type(2))) __bf16;
using floatx2  = __attribute__((ext_vector_type(2))) float;
using floatx4  = __attribute__((ext_vector_type(4))) float;
using floatx16 = __attribute__((ext_vector_type(16))) float;
using ushortx4 = __attribute__((ext_vector_type(4))) unsigned short;
using ushortx8 = __attribute__((ext_vector_type(8))) unsigned short;
using uintx4   = __attribute__((ext_vector_type(4))) unsigned int;

__device__ __forceinline__ ushortx4 cvt4(floatx4 f) {
    bf16x4 h = __builtin_convertvector(f, bf16x4);   // RNE packed cvt
    return __builtin_bit_cast(ushortx4, h);
}

__device__ __forceinline__ unsigned int pkbf16(float a, float b) {
    floatx2 f = {a, b};
    return __builtin_bit_cast(unsigned int, __builtin_convertvector(f, bf16x2));
}

// v_permlane32_swap_b32: x.lanes[32:63] <-> y.lanes[0:31]; both outputs used.
__device__ __forceinline__ void pl32swap(unsigned int& x, unsigned int& y) {
    __asm__ volatile("v_permlane32_swap_b32 %0, %1" : "+v"(x), "+v"(y));
}

// async global->LDS, 16B/lane; lds base wave-uniform (lane i -> base + i*16)
__device__ __forceinline__ void glds16(const unsigned short* g, unsigned short* l) {
    __builtin_amdgcn_global_load_lds(
        (const __attribute__((address_space(1))) unsigned int*)g,
        (__attribute__((address_space(3))) unsigned int*)l, 16, 0, 0);
}

// ---------------------------------------------------------------- projection
// grid = 3072: blockIdx = p*1024 + bh*32 + st. One 64x64 GEMM per block.
// Stores XOR-swizzled: logical 16B chunk c of row r -> physical c^(r&7).
__global__ __launch_bounds__(256) void proj_kernel(
    const float* __restrict__ xq, const float* __restrict__ xk, const float* __restrict__ xv,
    const float* __restrict__ Wq, const float* __restrict__ bq,
    const float* __restrict__ Wk, const float* __restrict__ bk,
    const float* __restrict__ Wv, const float* __restrict__ bv,
    unsigned short* __restrict__ qb, unsigned short* __restrict__ kb,
    unsigned short* __restrict__ vtb)
{
    __shared__ __align__(16) unsigned short Xb[64 * LDP];
    __shared__ __align__(16) unsigned short Wb[64 * LDP];
    __shared__ __align__(16) unsigned short Ob[64 * LDP];
    __shared__ float blds[64];

    const int t  = threadIdx.x;
    const int p  = blockIdx.x >> 10;
    const int bh = (blockIdx.x >> 5) & 31;
    const int st = blockIdx.x & 31;
    const int s0 = st * 64;
    const int b  = bh >> 4, h = bh & 15;
    const int lane = t & 63, w = t >> 6, quad = lane >> 4, l16 = lane & 15;

    const float* x    = (p == 0) ? xq : (p == 1) ? xk : xv;
    const float* W    = (p == 0) ? Wq : (p == 1) ? Wk : Wv;
    const float* bias = (p == 0) ? bq : (p == 1) ? bk : bv;

    #pragma unroll
    for (int i = 0; i < 4; ++i) {
        int idx = i * 1024 + t * 4;
        int row = idx >> 6, col = idx & 63;
        floatx4 xv4 = *(const floatx4*)(x + (((size_t)(b * SEQ + s0 + row) * NH + h) * DE + col));
        *(ushortx4*)&Xb[row * LDP + col] = cvt4(xv4);
        floatx4 wv4 = *(const floatx4*)(W + row * 64 + col);
        *(ushortx4*)&Wb[row * LDP + col] = cvt4(wv4);
    }
    if (t < 64) blds[t] = bias[t];
    __syncthreads();

    if (p < 2) {
        // A = W rows (m=f), B = X rows (n=s) -> D[f][s]
        bf16x8 a0 = *(const bf16x8*)&Wb[(w * 16 + l16) * LDP + quad * 8];
        bf16x8 a1 = *(const bf16x8*)&Wb[(w * 16 + l16) * LDP + 32 + quad * 8];
        floatx4 bf4 = *(const floatx4*)&blds[w * 16 + quad * 4];
        const float scale = (p == 0) ? 0.125f * LOG2E : 1.0f;  // Q in log2 domain
        #pragma unroll
        for (int nb = 0; nb < 4; ++nb) {
            bf16x8 b0 = *(const bf16x8*)&Xb[(nb * 16 + l16) * LDP + quad * 8];
            bf16x8 b1 = *(const bf16x8*)&Xb[(nb * 16 + l16) * LDP + 32 + quad * 8];
            floatx4 c = {0.f, 0.f, 0.f, 0.f};
            c = __builtin_amdgcn_mfma_f32_16x16x32_bf16(a0, b0, c, 0, 0, 0);
            c = __builtin_amdgcn_mfma_f32_16x16x32_bf16(a1, b1, c, 0, 0, 0);
            floatx4 v;
            v[0] = (c[0] + bf4[0]) * scale; v[1] = (c[1] + bf4[1]) * scale;
            v[2] = (c[2] + bf4[2]) * scale; v[3] = (c[3] + bf4[3]) * scale;
            *(ushortx4*)&Ob[(nb * 16 + l16) * LDP + w * 16 + quad * 4] = cvt4(v);  // Ob[s][f]
        }
    } else {
        // A = X rows (m=s), B = W rows (n=f) -> D[s][f]
        bf16x8 a0 = *(const bf16x8*)&Xb[(w * 16 + l16) * LDP + quad * 8];
        bf16x8 a1 = *(const bf16x8*)&Xb[(w * 16 + l16) * LDP + 32 + quad * 8];
        #pragma unroll
        for (int nb = 0; nb < 4; ++nb) {
            bf16x8 b0 = *(const bf16x8*)&Wb[(nb * 16 + l16) * LDP + quad * 8];
            bf16x8 b1 = *(const bf16x8*)&Wb[(nb * 16 + l16) * LDP + 32 + quad * 8];
            floatx4 c = {0.f, 0.f, 0.f, 0.f};
            c = __builtin_amdgcn_mfma_f32_16x16x32_bf16(a0, b0, c, 0, 0, 0);
            c = __builtin_amdgcn_mfma_f32_16x16x32_bf16(a1, b1, c, 0, 0, 0);
            float bw = blds[nb * 16 + l16];
            floatx4 v;
            v[0] = c[0] + bw; v[1] = c[1] + bw; v[2] = c[2] + bw; v[3] = c[3] + bw;
            *(ushortx4*)&Ob[(nb * 16 + l16) * LDP + w * 16 + quad * 4] = cvt4(v);  // Ob[f][s]
        }
    }
    __syncthreads();

    #pragma unroll
    for (int j = 0; j < 2; ++j) {
        int idx = j * 256 + t;
        int row = idx >> 3, c = idx & 7;
        int cp  = (c ^ (row & 7)) * 8;
        ushortx8 v = *(const ushortx8*)&Ob[row * LDP + c * 8];
        if (p < 2) {
            unsigned short* dst = (p == 0) ? qb : kb;
            *(ushortx8*)(dst + ((size_t)bh * SEQ + s0 + row) * DE + cp) = v;       // row = s
        } else {
            *(ushortx8*)(vtb + ((size_t)bh * DE + row) * SEQ + s0 + cp) = v;       // row = e
        }
    }
}

// ---------------------------------------------------------------- attention
// grid = (SEQ/128, BATCH*NH); block = 512 = 8 waves.
// wave w: qw = w&3 owns q-block qw*32..+31; kblk = w>>2 owns keys
// kblk*32..+31 of each 64-key tile. Partial O/l summed in epilogue.
__global__ __launch_bounds__(512, 4) void attn_kernel(
    const unsigned short* __restrict__ qb, const unsigned short* __restrict__ kb,
    const unsigned short* __restrict__ vtb, const int* __restrict__ mask,
    float* __restrict__ out)
{
    // Kl dbuf 16KB | Vl dbuf 16KB | Pq 16KB (Q stage) | Ml 512B
    __shared__ __align__(16) char smem[16384 + 16384 + 16384 + 512];
    unsigned short* Kl = (unsigned short*)smem;                 // [2][64*64]
    unsigned short* Vl = (unsigned short*)(smem + 16384);       // [2][64*64]
    unsigned short* Pq = (unsigned short*)(smem + 32768);       // 128*64 Q
    float*          Ml = (float*)(smem + 49152);                // [2][64]
    float*          Ol = (float*)smem;                          // epilogue 128*LDOF
    float*          Ll = (float*)(smem + 34816);                // epilogue 128*4

    const int t  = threadIdx.x;
    const int qt = blockIdx.x, bh = blockIdx.y;
    const int b  = bh >> 4, h = bh & 15;
    const int q0 = qt * 128;
    const int lane = t & 63, w = t >> 6;            // w in 0..7
    const int hi = lane >> 5, l31 = lane & 31;
    const int qw = w & 3, kblk = w >> 2;
    const int sw7 = l31 & 7;                        // row-swizzle key

    const unsigned short* kbase = kb + (size_t)bh * SEQ * DE;
    const unsigned short* vbase = vtb + (size_t)bh * DE * SEQ;
    const unsigned short* qsrc  = qb + ((size_t)bh * SEQ + q0) * DE;
    const int* mrow = mask + b * SEQ;

    // stage Q (2 loads/wave), K/V tile 0 (1+1 loads/wave) -- straight copies
    glds16(qsrc + (w * 16) * DE + lane * 8,      Pq + (w * 16) * 64);
    glds16(qsrc + (w * 16 + 8) * DE + lane * 8,  Pq + (w * 16 + 8) * 64);
    glds16(kbase + (size_t)(w * 8) * DE + lane * 8, Kl + w * 512);
    glds16(vbase + (size_t)(w * 8 + (lane >> 3)) * SEQ + (lane & 7) * 8, Vl + w * 512);
    if (t < 64) Ml[t] = mrow[t] ? -CSHIFT : -1e30f;  // CSHIFT folded into bias
    int mreg = (t < 64) ? mrow[64 + t] : 0;          // mask for tile 1
    __syncthreads();                                 // drains vmcnt -> Q/K/V in LDS

    // hoist Q B-fragments: Q[col=q=qw*32+l31][k=e = ks*16 + hi*8 + j]
    bf16x8 qf[4];
    #pragma unroll
    for (int ks = 0; ks < 4; ++ks)
        qf[ks] = *(const bf16x8*)&Pq[(qw * 32 + l31) * 64 + (((ks * 2 + hi) ^ sw7) * 8)];

    floatx16 o0, o1;                                // D[col=q][row=e], e-blocks 0/1
    #pragma unroll
    for (int i = 0; i < 16; ++i) { o0[i] = 0.f; o1[i] = 0.f; }
    float lp = 0.f;                                 // per-lane l partial (f32)

    for (int kt = 0; kt < NKT; ++kt) {
        const int cur = kt & 1, nxt = cur ^ 1;
        const unsigned short* Kc = Kl + cur * 4096;
        const unsigned short* Vc = Vl + cur * 4096;
        const float*          Mc = Ml + cur * 64;

        if (kt + 1 < NKT) {                         // prefetch tile kt+1
            const int k1 = (kt + 1) * 64;
            glds16(kbase + (size_t)(k1 + w * 8) * DE + lane * 8, Kl + nxt * 4096 + w * 512);
            glds16(vbase + (size_t)(w * 8 + (lane >> 3)) * SEQ + k1 + (lane & 7) * 8,
                   Vl + nxt * 4096 + w * 512);
            if (t < 64) Ml[nxt * 64 + t] = mreg ? -CSHIFT : -1e30f;
            mreg = (t < 64 && kt + 2 < NKT) ? mrow[(kt + 2) * 64 + t] : 0;
        }

        // C-init = mask bias: sc reg r maps to key_local = kblk*32 + (r&3)+8*(r>>2)+4*hi
        // -> floatx4 group g covers keys kblk*32 + 8g + 4hi + 0..3 (broadcast reads)
        floatx16 sc;
        #pragma unroll
        for (int g = 0; g < 4; ++g) {
            floatx4 mb = *(const floatx4*)&Mc[kblk * 32 + g * 8 + hi * 4];
            sc[4 * g + 0] = mb[0]; sc[4 * g + 1] = mb[1];
            sc[4 * g + 2] = mb[2]; sc[4 * g + 3] = mb[3];
        }
        // S^T block = K·Q^T (log2 domain): D[col=q][row=key], 32 keys of this kblk
        #pragma unroll
        for (int ks = 0; ks < 4; ++ks) {
            bf16x8 kf = *(const bf16x8*)&Kc[(kblk * 32 + l31) * 64 + (((ks * 2 + hi) ^ sw7) * 8)];
            sc = __builtin_amdgcn_mfma_f32_32x32x16_bf16(kf, qf[ks], sc, 0, 0, 0);
        }

        // P = exp2(s + bias) -- shift already in bias. l partial via f32 tree.
        #pragma unroll
        for (int r = 0; r < 16; ++r)
            sc[r] = __builtin_amdgcn_exp2f(sc[r]);
        {
            float a0 = sc[0] + sc[1],   a1 = sc[2] + sc[3];
            float a2 = sc[4] + sc[5],   a3 = sc[6] + sc[7];
            float a4 = sc[8] + sc[9],   a5 = sc[10] + sc[11];
            float a6 = sc[12] + sc[13], a7 = sc[14] + sc[15];
            lp += ((a0 + a1) + (a2 + a3)) + ((a4 + a5) + (a6 + a7));
        }

        // pack to bf16 + permlane32_swap -> PV B-frags, no LDS round-trip.
        // wd[j] = keys (pair) rows: j=0:{0,1}+4hi j=1:{2,3}+4hi j=2:8+{0,1}+4hi
        // j=3:8+{2,3}+4hi j=4..7 same +16. After swap(w0,w2),(w1,w3):
        // wd0..wd3 = B-frag elems (0,1)(2,3)(4,5)(6,7) for k-slice 0; wd4..7 slice 1.
        unsigned int wd0 = pkbf16(sc[0], sc[1]),   wd1 = pkbf16(sc[2], sc[3]);
        unsigned int wd2 = pkbf16(sc[4], sc[5]),   wd3 = pkbf16(sc[6], sc[7]);
        unsigned int wd4 = pkbf16(sc[8], sc[9]),   wd5 = pkbf16(sc[10], sc[11]);
        unsigned int wd6 = pkbf16(sc[12], sc[13]), wd7 = pkbf16(sc[14], sc[15]);
        pl32swap(wd0, wd2); pl32swap(wd1, wd3);
        pl32swap(wd4, wd6); pl32swap(wd5, wd7);
        uintx4 f0v = {wd0, wd1, wd2, wd3};
        uintx4 f1v = {wd4, wd5, wd6, wd7};
        bf16x8 pf0 = __builtin_bit_cast(bf16x8, f0v);
        bf16x8 pf1 = __builtin_bit_cast(bf16x8, f1v);

        // O^T += V^T · P^T: A = V^T[row=e][k=key kblk*32+s*16+hi*8+j]
        #pragma unroll
        for (int s = 0; s < 2; ++s) {
            const bf16x8 pf = s ? pf1 : pf0;
            const int cc = ((kblk * 4 + s * 2 + hi) ^ sw7) * 8;
            bf16x8 v0 = *(const bf16x8*)&Vc[l31 * 64 + cc];
            bf16x8 v1 = *(const bf16x8*)&Vc[(32 + l31) * 64 + cc];
            o0 = __builtin_amdgcn_mfma_f32_32x32x16_bf16(v0, pf, o0, 0, 0, 0);
            o1 = __builtin_amdgcn_mfma_f32_32x32x16_bf16(v1, pf, o1, 0, 0, 0);
        }

        __syncthreads();   // prefetch landed + all frag reads of cur done
    }

    // epilogue: combine kblk pair, normalize, coalesced store.
    const int qrow = qw * 32 + l31;
    Ll[qrow * 4 + kblk * 2 + hi] = lp;
    if (kblk == 1) {
        #pragma unroll
        for (int g = 0; g < 4; ++g) {
            floatx4 t0 = {o0[4*g+0], o0[4*g+1], o0[4*g+2], o0[4*g+3]};
            *(floatx4*)&Ol[qrow * LDOF + g * 8 + hi * 4] = t0;
            floatx4 t1 = {o1[4*g+0], o1[4*g+1], o1[4*g+2], o1[4*g+3]};
            *(floatx4*)&Ol[qrow * LDOF + 32 + g * 8 + hi * 4] = t1;
        }
    }
    __syncthreads();
    if (kblk == 0) {
        floatx4 lv = *(const floatx4*)&Ll[qrow * 4];
        float invl = __builtin_amdgcn_rcpf(lv[0] + lv[1] + lv[2] + lv[3]);
        #pragma unroll
        for (int g = 0; g < 4; ++g) {
            floatx4 t0 = *(floatx4*)&Ol[qrow * LDOF + g * 8 + hi * 4];
            t0[0] = (t0[0] + o0[4*g+0]) * invl; t0[1] = (t0[1] + o0[4*g+1]) * invl;
            t0[2] = (t0[2] + o0[4*g+2]) * invl; t0[3] = (t0[3] + o0[4*g+3]) * invl;
            *(floatx4*)&Ol[qrow * LDOF + g * 8 + hi * 4] = t0;
            floatx4 t1 = *(floatx4*)&Ol[qrow * LDOF + 32 + g * 8 + hi * 4];
            t1[0] = (t1[0] + o1[4*g+0]) * invl; t1[1] = (t1[1] + o1[4*g+1]) * invl;
            t1[2] = (t1[2] + o1[4*g+2]) * invl; t1[3] = (t1[3] + o1[4*g+3]) * invl;
            *(floatx4*)&Ol[qrow * LDOF + 32 + g * 8 + hi * 4] = t1;
        }
    }
    __syncthreads();
    {
        const int quad = lane >> 4, l16 = lane & 15;
        #pragma unroll
        for (int pass = 0; pass < 4; ++pass) {
            int rl  = w * 16 + pass * 4 + quad;
            int col = l16 * 4;
            floatx4 tv = *(const floatx4*)&Ol[rl * LDOF + col];
            *(floatx4*)(out + (((size_t)b * SEQ + q0 + rl) * NH + h) * DE + col) = tv;
        }
    }
}

extern "C" void kernel_launch(void* const* d_in, const int* in_sizes, int n_in,
                              void* d_out, int out_size, void* d_ws, size_t ws_size,
                              hipStream_t stream) {
    const float* query = (const float*)d_in[0];
    const float* key   = (const float*)d_in[1];
    const float* value = (const float*)d_in[2];
    const int*   mask  = (const int*)d_in[3];
    const float* Wq = (const float*)d_in[4];
    const float* bq = (const float*)d_in[5];
    const float* Wk = (const float*)d_in[6];
    const float* bk = (const float*)d_in[7];
    const float* Wv = (const float*)d_in[8];
    const float* bv = (const float*)d_in[9];

    const size_t tensor_elems = (size_t)BATCH * NH * SEQ * DE;
    unsigned short* qb  = (unsigned short*)d_ws;
    unsigned short* kb  = qb + tensor_elems;
    unsigned short* vtb = kb + tensor_elems;

    proj_kernel<<<dim3(3 * BATCH * NH * (SEQ / 64)), 256, 0, stream>>>(
        query, key, value, Wq, bq, Wk, bk, Wv, bv, qb, kb, vtb);
    attn_kernel<<<dim3(SEQ / 128, BATCH * NH), 512, 0, stream>>>(
        qb, kb, vtb, mask, (float*)d_out);
}

// Round 2
// 150.490 us; speedup vs baseline: 1.0534x; 1.0029x over previous
//
#include <hip/hip_runtime.h>

// SelfAttention B=2 S=2048 H=16 E=64, fp32 in/out, bf16 MFMA internally.
// Round 7: stall attack. R6 counters showed no pipe >43% busy (VALU 43,
// MFMA 30, LDS ~30) -> ~55% of cycles are barrier/latency stalls.
// Changes vs R6:
// (a) T4 counted-vmcnt: per k-tile the single __syncthreads (which drains
//     vmcnt(0), stalling on the just-issued prefetch) is replaced by
//     B1 -> issue prefetch (exactly 3 vmem per wave: K glds, V glds,
//     mask load made wave-uniform) -> s_waitcnt vmcnt(3) lgkmcnt(0) -> B2.
//     Prefetch stays in flight across the barrier; we wait only for the
//     PREVIOUS tile's loads. Tail iteration drains vmcnt(0).
// (b) T5 s_setprio(1) around the QK and PV MFMA clusters: waves in the
//     exp2 phase yield issue priority to waves in the MFMA phase.
// (c) softmax denominator l moved off the VALU pipe: 15-add tree replaced
//     by 2 ones-A MFMAs into persistent acc_l (bf16-P-consistent).
// Retained from R6: 32x32x16 MFMA, 4 qblk x 2 kblk wave split, in-register
// P via cvt_pk + v_permlane32_swap_b32, CSHIFT folded into mask bias,
// fixed-shift log2-domain softmax (LOG2E folded into Q at proj),
// global_load_lds staging, double-buffered K/V, XOR-swizzled gmem layout,
// proj kernel unchanged.

#define BATCH 2
#define SEQ   2048
#define NH    16
#define DE    64
#define LDP   72     // proj internal tile stride
#define LDOF  68     // O f32 epilogue stride
#define NKT   (SEQ / 64)
#define LOG2E 1.44269504088896340736f
#define CSHIFT 16.0f

using bf16x8   = __attribute__((ext_vector_type(8))) __bf16;
using bf16x4   = __attribute__((ext_vector_type(4))) __bf16;
using bf16x2   = __attribute__((ext_vector_type(2))) __bf16;
using floatx2  = __attribute__((ext_vector_type(2))) float;
using floatx4  = __attribute__((ext_vector_type(4))) float;
using floatx16 = __attribute__((ext_vector_type(16))) float;
using ushortx4 = __attribute__((ext_vector_type(4))) unsigned short;
using ushortx8 = __attribute__((ext_vector_type(8))) unsigned short;
using uintx4   = __attribute__((ext_vector_type(4))) unsigned int;

__device__ __forceinline__ ushortx4 cvt4(floatx4 f) {
    bf16x4 h = __builtin_convertvector(f, bf16x4);   // RNE packed cvt
    return __builtin_bit_cast(ushortx4, h);
}

__device__ __forceinline__ unsigned int pkbf16(float a, float b) {
    floatx2 f = {a, b};
    return __builtin_bit_cast(unsigned int, __builtin_convertvector(f, bf16x2));
}

// v_permlane32_swap_b32: x.lanes[32:63] <-> y.lanes[0:31]; both outputs used.
__device__ __forceinline__ void pl32swap(unsigned int& x, unsigned int& y) {
    __asm__ volatile("v_permlane32_swap_b32 %0, %1" : "+v"(x), "+v"(y));
}

// async global->LDS, 16B/lane; lds base wave-uniform (lane i -> base + i*16)
__device__ __forceinline__ void glds16(const unsigned short* g, unsigned short* l) {
    __builtin_amdgcn_global_load_lds(
        (const __attribute__((address_space(1))) unsigned int*)g,
        (__attribute__((address_space(3))) unsigned int*)l, 16, 0, 0);
}

// ---------------------------------------------------------------- projection
// grid = 3072: blockIdx = p*1024 + bh*32 + st. One 64x64 GEMM per block.
// Stores XOR-swizzled: logical 16B chunk c of row r -> physical c^(r&7).
__global__ __launch_bounds__(256) void proj_kernel(
    const float* __restrict__ xq, const float* __restrict__ xk, const float* __restrict__ xv,
    const float* __restrict__ Wq, const float* __restrict__ bq,
    const float* __restrict__ Wk, const float* __restrict__ bk,
    const float* __restrict__ Wv, const float* __restrict__ bv,
    unsigned short* __restrict__ qb, unsigned short* __restrict__ kb,
    unsigned short* __restrict__ vtb)
{
    __shared__ __align__(16) unsigned short Xb[64 * LDP];
    __shared__ __align__(16) unsigned short Wb[64 * LDP];
    __shared__ __align__(16) unsigned short Ob[64 * LDP];
    __shared__ float blds[64];

    const int t  = threadIdx.x;
    const int p  = blockIdx.x >> 10;
    const int bh = (blockIdx.x >> 5) & 31;
    const int st = blockIdx.x & 31;
    const int s0 = st * 64;
    const int b  = bh >> 4, h = bh & 15;
    const int lane = t & 63, w = t >> 6, quad = lane >> 4, l16 = lane & 15;

    const float* x    = (p == 0) ? xq : (p == 1) ? xk : xv;
    const float* W    = (p == 0) ? Wq : (p == 1) ? Wk : Wv;
    const float* bias = (p == 0) ? bq : (p == 1) ? bk : bv;

    #pragma unroll
    for (int i = 0; i < 4; ++i) {
        int idx = i * 1024 + t * 4;
        int row = idx >> 6, col = idx & 63;
        floatx4 xv4 = *(const floatx4*)(x + (((size_t)(b * SEQ + s0 + row) * NH + h) * DE + col));
        *(ushortx4*)&Xb[row * LDP + col] = cvt4(xv4);
        floatx4 wv4 = *(const floatx4*)(W + row * 64 + col);
        *(ushortx4*)&Wb[row * LDP + col] = cvt4(wv4);
    }
    if (t < 64) blds[t] = bias[t];
    __syncthreads();

    if (p < 2) {
        // A = W rows (m=f), B = X rows (n=s) -> D[f][s]
        bf16x8 a0 = *(const bf16x8*)&Wb[(w * 16 + l16) * LDP + quad * 8];
        bf16x8 a1 = *(const bf16x8*)&Wb[(w * 16 + l16) * LDP + 32 + quad * 8];
        floatx4 bf4 = *(const floatx4*)&blds[w * 16 + quad * 4];
        const float scale = (p == 0) ? 0.125f * LOG2E : 1.0f;  // Q in log2 domain
        #pragma unroll
        for (int nb = 0; nb < 4; ++nb) {
            bf16x8 b0 = *(const bf16x8*)&Xb[(nb * 16 + l16) * LDP + quad * 8];
            bf16x8 b1 = *(const bf16x8*)&Xb[(nb * 16 + l16) * LDP + 32 + quad * 8];
            floatx4 c = {0.f, 0.f, 0.f, 0.f};
            c = __builtin_amdgcn_mfma_f32_16x16x32_bf16(a0, b0, c, 0, 0, 0);
            c = __builtin_amdgcn_mfma_f32_16x16x32_bf16(a1, b1, c, 0, 0, 0);
            floatx4 v;
            v[0] = (c[0] + bf4[0]) * scale; v[1] = (c[1] + bf4[1]) * scale;
            v[2] = (c[2] + bf4[2]) * scale; v[3] = (c[3] + bf4[3]) * scale;
            *(ushortx4*)&Ob[(nb * 16 + l16) * LDP + w * 16 + quad * 4] = cvt4(v);  // Ob[s][f]
        }
    } else {
        // A = X rows (m=s), B = W rows (n=f) -> D[s][f]
        bf16x8 a0 = *(const bf16x8*)&Xb[(w * 16 + l16) * LDP + quad * 8];
        bf16x8 a1 = *(const bf16x8*)&Xb[(w * 16 + l16) * LDP + 32 + quad * 8];
        #pragma unroll
        for (int nb = 0; nb < 4; ++nb) {
            bf16x8 b0 = *(const bf16x8*)&Wb[(nb * 16 + l16) * LDP + quad * 8];
            bf16x8 b1 = *(const bf16x8*)&Wb[(nb * 16 + l16) * LDP + 32 + quad * 8];
            floatx4 c = {0.f, 0.f, 0.f, 0.f};
            c = __builtin_amdgcn_mfma_f32_16x16x32_bf16(a0, b0, c, 0, 0, 0);
            c = __builtin_amdgcn_mfma_f32_16x16x32_bf16(a1, b1, c, 0, 0, 0);
            float bw = blds[nb * 16 + l16];
            floatx4 v;
            v[0] = c[0] + bw; v[1] = c[1] + bw; v[2] = c[2] + bw; v[3] = c[3] + bw;
            *(ushortx4*)&Ob[(nb * 16 + l16) * LDP + w * 16 + quad * 4] = cvt4(v);  // Ob[f][s]
        }
    }
    __syncthreads();

    #pragma unroll
    for (int j = 0; j < 2; ++j) {
        int idx = j * 256 + t;
        int row = idx >> 3, c = idx & 7;
        int cp  = (c ^ (row & 7)) * 8;
        ushortx8 v = *(const ushortx8*)&Ob[row * LDP + c * 8];
        if (p < 2) {
            unsigned short* dst = (p == 0) ? qb : kb;
            *(ushortx8*)(dst + ((size_t)bh * SEQ + s0 + row) * DE + cp) = v;       // row = s
        } else {
            *(ushortx8*)(vtb + ((size_t)bh * DE + row) * SEQ + s0 + cp) = v;       // row = e
        }
    }
}

// ---------------------------------------------------------------- attention
// grid = (SEQ/128, BATCH*NH); block = 512 = 8 waves.
// wave w: qw = w&3 owns q-block qw*32..+31; kblk = w>>2 owns keys
// kblk*32..+31 of each 64-key tile. Partial O/l summed in epilogue.
__global__ __launch_bounds__(512, 4) void attn_kernel(
    const unsigned short* __restrict__ qb, const unsigned short* __restrict__ kb,
    const unsigned short* __restrict__ vtb, const int* __restrict__ mask,
    float* __restrict__ out)
{
    // Kl dbuf 16KB | Vl dbuf 16KB | Pq 16KB (Q stage) | Ml 512B
    __shared__ __align__(16) char smem[16384 + 16384 + 16384 + 512];
    unsigned short* Kl = (unsigned short*)smem;                 // [2][64*64]
    unsigned short* Vl = (unsigned short*)(smem + 16384);       // [2][64*64]
    unsigned short* Pq = (unsigned short*)(smem + 32768);       // 128*64 Q
    float*          Ml = (float*)(smem + 49152);                // [2][64]
    float*          Ol = (float*)smem;                          // epilogue 128*LDOF
    float*          Ll = (float*)(smem + 34816);                // epilogue 128*2

    const int t  = threadIdx.x;
    const int qt = blockIdx.x, bh = blockIdx.y;
    const int b  = bh >> 4, h = bh & 15;
    const int q0 = qt * 128;
    const int lane = t & 63, w = t >> 6;            // w in 0..7
    const int hi = lane >> 5, l31 = lane & 31;
    const int qw = w & 3, kblk = w >> 2;
    const int sw7 = l31 & 7;                        // row-swizzle key

    const unsigned short* kbase = kb + (size_t)bh * SEQ * DE;
    const unsigned short* vbase = vtb + (size_t)bh * DE * SEQ;
    const unsigned short* qsrc  = qb + ((size_t)bh * SEQ + q0) * DE;
    const int* mrow = mask + b * SEQ;

    // stage Q (2 loads/wave), K/V tile 0 (1+1 loads/wave) -- straight copies
    glds16(qsrc + (w * 16) * DE + lane * 8,      Pq + (w * 16) * 64);
    glds16(qsrc + (w * 16 + 8) * DE + lane * 8,  Pq + (w * 16 + 8) * 64);
    glds16(kbase + (size_t)(w * 8) * DE + lane * 8, Kl + w * 512);
    glds16(vbase + (size_t)(w * 8 + (lane >> 3)) * SEQ + (lane & 7) * 8, Vl + w * 512);
    if (w == 0) Ml[lane] = mrow[lane] ? -CSHIFT : -1e30f;  // tile-0 bias
    int mreg = mrow[64 + lane];                     // tile-1 mask (all waves, uniform vmem)
    __syncthreads();                                // prologue: full drain, Q/K/V in LDS

    // hoist Q B-fragments: Q[col=q=qw*32+l31][k=e = ks*16 + hi*8 + j]
    bf16x8 qf[4];
    #pragma unroll
    for (int ks = 0; ks < 4; ++ks)
        qf[ks] = *(const bf16x8*)&Pq[(qw * 32 + l31) * 64 + (((ks * 2 + hi) ^ sw7) * 8)];

    bf16x8 onesf;
    #pragma unroll
    for (int i = 0; i < 8; ++i) onesf[i] = (__bf16)1.0f;

    floatx16 o0, o1, acc_l;                         // D[col=q][row=e] + l accumulator
    #pragma unroll
    for (int i = 0; i < 16; ++i) { o0[i] = 0.f; o1[i] = 0.f; acc_l[i] = 0.f; }

    for (int kt = 0; kt < NKT; ++kt) {
        const int cur = kt & 1, nxt = cur ^ 1;
        const unsigned short* Kc = Kl + cur * 4096;
        const unsigned short* Vc = Vl + cur * 4096;
        const float*          Mc = Ml + cur * 64;

        // B1: all waves done READING buf[nxt] (= cur of kt-1); safe to overwrite.
        __builtin_amdgcn_sched_barrier(0);
        __builtin_amdgcn_s_barrier();

        if (kt + 1 < NKT) {                         // prefetch tile kt+1 (3 vmem/wave)
            const int k1 = (kt + 1) * 64;
            glds16(kbase + (size_t)(k1 + w * 8) * DE + lane * 8, Kl + nxt * 4096 + w * 512);
            glds16(vbase + (size_t)(w * 8 + (lane >> 3)) * SEQ + k1 + (lane & 7) * 8,
                   Vl + nxt * 4096 + w * 512);
            if (w == 0) Ml[nxt * 64 + lane] = mreg ? -CSHIFT : -1e30f;
            const int midx = (kt + 2 < NKT) ? ((kt + 2) * 64 + lane) : lane;
            mreg = mrow[midx];                      // uniform: every wave, every iter
            // wait for PREVIOUS tile's 3 loads only; current 3 stay in flight
            __asm__ volatile("s_waitcnt vmcnt(3) lgkmcnt(0)" ::: "memory");
        } else {
            __asm__ volatile("s_waitcnt vmcnt(0) lgkmcnt(0)" ::: "memory");
        }
        // B2: buf[cur] data ready on all waves.
        __builtin_amdgcn_s_barrier();
        __builtin_amdgcn_sched_barrier(0);

        // C-init = mask bias: sc reg r maps to key_local = kblk*32 + (r&3)+8*(r>>2)+4*hi
        floatx16 sc;
        #pragma unroll
        for (int g = 0; g < 4; ++g) {
            floatx4 mb = *(const floatx4*)&Mc[kblk * 32 + g * 8 + hi * 4];
            sc[4 * g + 0] = mb[0]; sc[4 * g + 1] = mb[1];
            sc[4 * g + 2] = mb[2]; sc[4 * g + 3] = mb[3];
        }
        // S^T block = K·Q^T (log2 domain): D[col=q][row=key], 32 keys of this kblk
        __builtin_amdgcn_s_setprio(1);
        #pragma unroll
        for (int ks = 0; ks < 4; ++ks) {
            bf16x8 kf = *(const bf16x8*)&Kc[(kblk * 32 + l31) * 64 + (((ks * 2 + hi) ^ sw7) * 8)];
            sc = __builtin_amdgcn_mfma_f32_32x32x16_bf16(kf, qf[ks], sc, 0, 0, 0);
        }
        __builtin_amdgcn_s_setprio(0);

        // P = exp2(s + bias) -- shift already folded into bias.
        #pragma unroll
        for (int r = 0; r < 16; ++r)
            sc[r] = __builtin_amdgcn_exp2f(sc[r]);

        // pack to bf16 + permlane32_swap -> PV B-frags, no LDS round-trip.
        unsigned int wd0 = pkbf16(sc[0], sc[1]),   wd1 = pkbf16(sc[2], sc[3]);
        unsigned int wd2 = pkbf16(sc[4], sc[5]),   wd3 = pkbf16(sc[6], sc[7]);
        unsigned int wd4 = pkbf16(sc[8], sc[9]),   wd5 = pkbf16(sc[10], sc[11]);
        unsigned int wd6 = pkbf16(sc[12], sc[13]), wd7 = pkbf16(sc[14], sc[15]);
        pl32swap(wd0, wd2); pl32swap(wd1, wd3);
        pl32swap(wd4, wd6); pl32swap(wd5, wd7);
        uintx4 f0v = {wd0, wd1, wd2, wd3};
        uintx4 f1v = {wd4, wd5, wd6, wd7};
        bf16x8 pf0 = __builtin_bit_cast(bf16x8, f0v);
        bf16x8 pf1 = __builtin_bit_cast(bf16x8, f1v);

        // O^T += V^T · P^T; l via ones-A MFMA (off the VALU pipe, bf16-P-consistent)
        __builtin_amdgcn_s_setprio(1);
        #pragma unroll
        for (int s = 0; s < 2; ++s) {
            const bf16x8 pf = s ? pf1 : pf0;
            const int cc = ((kblk * 4 + s * 2 + hi) ^ sw7) * 8;
            bf16x8 v0 = *(const bf16x8*)&Vc[l31 * 64 + cc];
            bf16x8 v1 = *(const bf16x8*)&Vc[(32 + l31) * 64 + cc];
            o0 = __builtin_amdgcn_mfma_f32_32x32x16_bf16(v0, pf, o0, 0, 0, 0);
            o1 = __builtin_amdgcn_mfma_f32_32x32x16_bf16(v1, pf, o1, 0, 0, 0);
        }
        acc_l = __builtin_amdgcn_mfma_f32_32x32x16_bf16(onesf, pf0, acc_l, 0, 0, 0);
        acc_l = __builtin_amdgcn_mfma_f32_32x32x16_bf16(onesf, pf1, acc_l, 0, 0, 0);
        __builtin_amdgcn_s_setprio(0);
    }

    // epilogue: combine kblk pair, normalize, coalesced store.
    __syncthreads();                                // all compute done; smem reusable
    const int qrow = qw * 32 + l31;
    if (hi == 0) Ll[qrow * 2 + kblk] = acc_l[0];    // all 16 regs identical; hi dup
    if (kblk == 1) {
        #pragma unroll
        for (int g = 0; g < 4; ++g) {
            floatx4 t0 = {o0[4*g+0], o0[4*g+1], o0[4*g+2], o0[4*g+3]};
            *(floatx4*)&Ol[qrow * LDOF + g * 8 + hi * 4] = t0;
            floatx4 t1 = {o1[4*g+0], o1[4*g+1], o1[4*g+2], o1[4*g+3]};
            *(floatx4*)&Ol[qrow * LDOF + 32 + g * 8 + hi * 4] = t1;
        }
    }
    __syncthreads();
    if (kblk == 0) {
        float invl = __builtin_amdgcn_rcpf(Ll[qrow * 2] + Ll[qrow * 2 + 1]);
        #pragma unroll
        for (int g = 0; g < 4; ++g) {
            floatx4 t0 = *(floatx4*)&Ol[qrow * LDOF + g * 8 + hi * 4];
            t0[0] = (t0[0] + o0[4*g+0]) * invl; t0[1] = (t0[1] + o0[4*g+1]) * invl;
            t0[2] = (t0[2] + o0[4*g+2]) * invl; t0[3] = (t0[3] + o0[4*g+3]) * invl;
            *(floatx4*)&Ol[qrow * LDOF + g * 8 + hi * 4] = t0;
            floatx4 t1 = *(floatx4*)&Ol[qrow * LDOF + 32 + g * 8 + hi * 4];
            t1[0] = (t1[0] + o1[4*g+0]) * invl; t1[1] = (t1[1] + o1[4*g+1]) * invl;
            t1[2] = (t1[2] + o1[4*g+2]) * invl; t1[3] = (t1[3] + o1[4*g+3]) * invl;
            *(floatx4*)&Ol[qrow * LDOF + 32 + g * 8 + hi * 4] = t1;
        }
    }
    __syncthreads();
    {
        const int quad = lane >> 4, l16 = lane & 15;
        #pragma unroll
        for (int pass = 0; pass < 4; ++pass) {
            int rl  = w * 16 + pass * 4 + quad;
            int col = l16 * 4;
            floatx4 tv = *(const floatx4*)&Ol[rl * LDOF + col];
            *(floatx4*)(out + (((size_t)b * SEQ + q0 + rl) * NH + h) * DE + col) = tv;
        }
    }
}

extern "C" void kernel_launch(void* const* d_in, const int* in_sizes, int n_in,
                              void* d_out, int out_size, void* d_ws, size_t ws_size,
                              hipStream_t stream) {
    const float* query = (const float*)d_in[0];
    const float* key   = (const float*)d_in[1];
    const float* value = (const float*)d_in[2];
    const int*   mask  = (const int*)d_in[3];
    const float* Wq = (const float*)d_in[4];
    const float* bq = (const float*)d_in[5];
    const float* Wk = (const float*)d_in[6];
    const float* bk = (const float*)d_in[7];
    const float* Wv = (const float*)d_in[8];
    const float* bv = (const float*)d_in[9];

    const size_t tensor_elems = (size_t)BATCH * NH * SEQ * DE;
    unsigned short* qb  = (unsigned short*)d_ws;
    unsigned short* kb  = qb + tensor_elems;
    unsigned short* vtb = kb + tensor_elems;

    proj_kernel<<<dim3(3 * BATCH * NH * (SEQ / 64)), 256, 0, stream>>>(
        query, key, value, Wq, bq, Wk, bk, Wv, bv, qb, kb, vtb);
    attn_kernel<<<dim3(SEQ / 128, BATCH * NH), 512, 0, stream>>>(
        qb, kb, vtb, mask, (float*)d_out);
}